// Round 4
// baseline (235.409 us; speedup 1.0000x reference)
//
#include <hip/hip_runtime.h>

#define HDIM 512
#define LDIM 1024
#define BDIM 64

// ---------------------------------------------------------------------------
// Kernel 1: hproj[b,h] = sum_o hidden[b,o] * W[o,h]   (64 x 512)
// grid 64 (one block per b), block 128. Thread t owns 4 consecutive h via
// float4 loads of W row-slices: wave reads 1KB contiguous per o. Four
// independent FMA chains (acc.x/y/z/w) hide VALU latency.
// ---------------------------------------------------------------------------
__global__ __launch_bounds__(128) void hproj_kernel(
    const float* __restrict__ hidden, const float* __restrict__ W,
    float* __restrict__ hproj) {
  __shared__ float sh[HDIM];
  const int b   = blockIdx.x;
  const int tid = threadIdx.x;
  ((float4*)sh)[tid] = ((const float4*)(hidden + b * HDIM))[tid];
  __syncthreads();

  const float4* Wv = (const float4*)W;  // W[o*512 + 4t] == Wv[o*128 + t]
  float4 acc = make_float4(0.f, 0.f, 0.f, 0.f);
  #pragma unroll 8
  for (int o = 0; o < HDIM; ++o) {
    const float  s = sh[o];
    const float4 w = Wv[o * 128 + tid];
    acc.x += s * w.x; acc.y += s * w.y; acc.z += s * w.z; acc.w += s * w.w;
  }
  ((float4*)(hproj + b * HDIM))[tid] = acc;
}

// ---------------------------------------------------------------------------
// Kernel 2: energies[b,l] = sum_h hproj[b,h] * enc[l,b,h]
// One wave per TWO rows sharing b: (l0, b) and (l0+512, b). hproj loaded
// once per wave (halves L2 re-reads). enc rows are 2KB contiguous; lane
// reads float4 at h=4*lane and h=4*(lane+64) -> 1KB coalesced bursts.
// ---------------------------------------------------------------------------
__global__ __launch_bounds__(256) void energies_kernel(
    const float* __restrict__ enc, const float* __restrict__ hproj,
    float* __restrict__ energies) {
  const int wave = blockIdx.x * 4 + (threadIdx.x >> 6);  // 0..32767
  const int lane = threadIdx.x & 63;
  const int b  = wave & (BDIM - 1);
  const int l0 = wave >> 6;                              // 0..511

  const float4* hp = (const float4*)(hproj + b * HDIM);
  const float4  h0 = hp[lane];
  const float4  h1 = hp[lane + 64];

  const float4* r0 = (const float4*)(enc + (size_t)(l0 * BDIM + b) * HDIM);
  const float4* r1 = (const float4*)(enc + (size_t)((l0 + 512) * BDIM + b) * HDIM);

  const float4 a0 = r0[lane];
  const float4 a1 = r0[lane + 64];
  const float4 c0 = r1[lane];
  const float4 c1 = r1[lane + 64];

  float s0 = a0.x * h0.x + a0.y * h0.y + a0.z * h0.z + a0.w * h0.w +
             a1.x * h1.x + a1.y * h1.y + a1.z * h1.z + a1.w * h1.w;
  float s1 = c0.x * h0.x + c0.y * h0.y + c0.z * h0.z + c0.w * h0.w +
             c1.x * h1.x + c1.y * h1.y + c1.z * h1.z + c1.w * h1.w;

  #pragma unroll
  for (int off = 32; off > 0; off >>= 1) {
    s0 += __shfl_down(s0, off, 64);
    s1 += __shfl_down(s1, off, 64);
  }

  if (lane == 0) {
    energies[b * LDIM + l0]       = s0;
    energies[b * LDIM + l0 + 512] = s1;
  }
}

// ---------------------------------------------------------------------------
// Kernel 3: row softmax over L=1024, one block (256 thr) per b.
// ---------------------------------------------------------------------------
__global__ __launch_bounds__(256) void softmax_kernel(
    const float* __restrict__ energies, float* __restrict__ out) {
  const int b    = blockIdx.x;
  const int tid  = threadIdx.x;
  const int wid  = tid >> 6;
  const int lane = tid & 63;

  float4 v = ((const float4*)(energies + b * LDIM))[tid];

  float m = fmaxf(fmaxf(v.x, v.y), fmaxf(v.z, v.w));
  #pragma unroll
  for (int off = 32; off > 0; off >>= 1) m = fmaxf(m, __shfl_xor(m, off, 64));
  __shared__ float sm[4];
  if (lane == 0) sm[wid] = m;
  __syncthreads();
  m = fmaxf(fmaxf(sm[0], sm[1]), fmaxf(sm[2], sm[3]));

  float e0 = __expf(v.x - m), e1 = __expf(v.y - m);
  float e2 = __expf(v.z - m), e3 = __expf(v.w - m);
  float s = (e0 + e1) + (e2 + e3);
  #pragma unroll
  for (int off = 32; off > 0; off >>= 1) s += __shfl_xor(s, off, 64);
  __shared__ float ss[4];
  if (lane == 0) ss[wid] = s;
  __syncthreads();
  s = (ss[0] + ss[1]) + (ss[2] + ss[3]);

  const float inv = 1.0f / s;
  ((float4*)(out + b * LDIM))[tid] =
      make_float4(e0 * inv, e1 * inv, e2 * inv, e3 * inv);
}

extern "C" void kernel_launch(void* const* d_in, const int* in_sizes, int n_in,
                              void* d_out, int out_size, void* d_ws, size_t ws_size,
                              hipStream_t stream) {
  const float* hidden = (const float*)d_in[0];  // [1,B,H]
  const float* enc    = (const float*)d_in[1];  // [L,B,H]
  const float* W      = (const float*)d_in[2];  // [H,H]
  // d_in[3] = bias: constant along the softmax axis after the dot -> dropped.

  float* out      = (float*)d_out;              // [B,1,L]
  float* hproj    = (float*)d_ws;                               // 128 KB
  float* energies = (float*)((char*)d_ws + BDIM * HDIM * 4);    // 256 KB

  hproj_kernel<<<BDIM, 128, 0, stream>>>(hidden, W, hproj);
  energies_kernel<<<(LDIM * BDIM) / 8, 256, 0, stream>>>(enc, hproj, energies);
  softmax_kernel<<<BDIM, 256, 0, stream>>>(energies, out);
}

// Round 5
// 233.533 us; speedup vs baseline: 1.0080x; 1.0080x over previous
//
#include <hip/hip_runtime.h>

#define HDIM 512
#define LDIM 1024
#define BDIM 64

// ---------------------------------------------------------------------------
// Kernel 1: hproj[b,h] = sum_o hidden[b,o] * W[o,h]   (64 x 512)
// grid 256 = (b, h-quarter), block 64 (1 wave). Each wave computes 128
// consecutive h for one b: per o, the wave reads a 512B coalesced slice of
// W's row (L2-resident after first touch). 256 waves spread over 256 CUs
// vs the previous 64-block version (half the chip idle, latency-bound).
// ---------------------------------------------------------------------------
__global__ __launch_bounds__(64) void hproj_kernel(
    const float* __restrict__ hidden, const float* __restrict__ W,
    float* __restrict__ hproj) {
  __shared__ float sh[HDIM];
  const int b = blockIdx.x >> 2;   // 0..63
  const int q = blockIdx.x & 3;    // h-quarter, 0..3
  const int t = threadIdx.x;       // 0..63

  ((float4*)sh)[t]      = ((const float4*)(hidden + b * HDIM))[t];
  ((float4*)sh)[t + 64] = ((const float4*)(hidden + b * HDIM))[t + 64];
  __syncthreads();

  // W[o*512 + q*128 + 2t] viewed as float2: index o*256 + q*64 + t
  const float2* W2 = (const float2*)W;
  float2 acc = make_float2(0.f, 0.f);
  #pragma unroll 8
  for (int o = 0; o < HDIM; ++o) {
    const float  s = sh[o];
    const float2 w = W2[o * 256 + q * 64 + t];
    acc.x += s * w.x;
    acc.y += s * w.y;
  }
  ((float2*)(hproj + b * HDIM + q * 128))[t] = acc;
}

// ---------------------------------------------------------------------------
// Kernel 2: energies[b,l] = sum_h hproj[b,h] * enc[l,b,h]
// One wave per TWO rows sharing b: (l0, b) and (l0+512, b). hproj loaded
// once per wave. enc rows are 2KB contiguous; consecutive waves in a block
// handle consecutive b at the same l0 -> 8KB contiguous bursts per block.
// ---------------------------------------------------------------------------
__global__ __launch_bounds__(256) void energies_kernel(
    const float* __restrict__ enc, const float* __restrict__ hproj,
    float* __restrict__ energies) {
  const int wave = blockIdx.x * 4 + (threadIdx.x >> 6);  // 0..32767
  const int lane = threadIdx.x & 63;
  const int b  = wave & (BDIM - 1);
  const int l0 = wave >> 6;                              // 0..511

  const float4* hp = (const float4*)(hproj + b * HDIM);
  const float4  h0 = hp[lane];
  const float4  h1 = hp[lane + 64];

  const float4* r0 = (const float4*)(enc + (size_t)(l0 * BDIM + b) * HDIM);
  const float4* r1 = (const float4*)(enc + (size_t)((l0 + 512) * BDIM + b) * HDIM);

  const float4 a0 = r0[lane];
  const float4 a1 = r0[lane + 64];
  const float4 c0 = r1[lane];
  const float4 c1 = r1[lane + 64];

  float s0 = a0.x * h0.x + a0.y * h0.y + a0.z * h0.z + a0.w * h0.w +
             a1.x * h1.x + a1.y * h1.y + a1.z * h1.z + a1.w * h1.w;
  float s1 = c0.x * h0.x + c0.y * h0.y + c0.z * h0.z + c0.w * h0.w +
             c1.x * h1.x + c1.y * h1.y + c1.z * h1.z + c1.w * h1.w;

  #pragma unroll
  for (int off = 32; off > 0; off >>= 1) {
    s0 += __shfl_down(s0, off, 64);
    s1 += __shfl_down(s1, off, 64);
  }

  if (lane == 0) {
    energies[b * LDIM + l0]       = s0;
    energies[b * LDIM + l0 + 512] = s1;
  }
}

// ---------------------------------------------------------------------------
// Kernel 3: row softmax over L=1024, one block (256 thr) per b.
// ---------------------------------------------------------------------------
__global__ __launch_bounds__(256) void softmax_kernel(
    const float* __restrict__ energies, float* __restrict__ out) {
  const int b    = blockIdx.x;
  const int tid  = threadIdx.x;
  const int wid  = tid >> 6;
  const int lane = tid & 63;

  float4 v = ((const float4*)(energies + b * LDIM))[tid];

  float m = fmaxf(fmaxf(v.x, v.y), fmaxf(v.z, v.w));
  #pragma unroll
  for (int off = 32; off > 0; off >>= 1) m = fmaxf(m, __shfl_xor(m, off, 64));
  __shared__ float sm[4];
  if (lane == 0) sm[wid] = m;
  __syncthreads();
  m = fmaxf(fmaxf(sm[0], sm[1]), fmaxf(sm[2], sm[3]));

  float e0 = __expf(v.x - m), e1 = __expf(v.y - m);
  float e2 = __expf(v.z - m), e3 = __expf(v.w - m);
  float s = (e0 + e1) + (e2 + e3);
  #pragma unroll
  for (int off = 32; off > 0; off >>= 1) s += __shfl_xor(s, off, 64);
  __shared__ float ss[4];
  if (lane == 0) ss[wid] = s;
  __syncthreads();
  s = (ss[0] + ss[1]) + (ss[2] + ss[3]);

  const float inv = 1.0f / s;
  ((float4*)(out + b * LDIM))[tid] =
      make_float4(e0 * inv, e1 * inv, e2 * inv, e3 * inv);
}

extern "C" void kernel_launch(void* const* d_in, const int* in_sizes, int n_in,
                              void* d_out, int out_size, void* d_ws, size_t ws_size,
                              hipStream_t stream) {
  const float* hidden = (const float*)d_in[0];  // [1,B,H]
  const float* enc    = (const float*)d_in[1];  // [L,B,H]
  const float* W      = (const float*)d_in[2];  // [H,H]
  // d_in[3] = bias: constant along the softmax axis after the dot -> dropped.

  float* out      = (float*)d_out;              // [B,1,L]
  float* hproj    = (float*)d_ws;                               // 128 KB
  float* energies = (float*)((char*)d_ws + BDIM * HDIM * 4);    // 256 KB

  hproj_kernel<<<BDIM * 4, 64, 0, stream>>>(hidden, W, hproj);
  energies_kernel<<<(LDIM * BDIM) / 8, 256, 0, stream>>>(enc, hproj, energies);
  softmax_kernel<<<BDIM, 256, 0, stream>>>(energies, out);
}